// Round 1
// baseline (952.126 us; speedup 1.0000x reference)
//
#include <hip/hip_runtime.h>
#include <math.h>

#define TT 288
#define LL 366
#define BBn 2
#define NN (BBn*LL)   // 732
#define DD 32
#define EDm 64
#define DSm 16
#define DCm 4
#define XJ 34         // dt_rank + 2*DS
#define XST 36        // padded dbc row stride

__device__ __forceinline__ float sigm_(float x){ return 1.0f/(1.0f+__expf(-x)); }
__device__ __forceinline__ float silu_(float x){ return x*sigm_(x); }
__device__ __forceinline__ float softpl_(float x){ return fmaxf(x,0.0f) + __logf(1.0f + __expf(-fabsf(x))); }

// ---------------- embed: X[nl,t,d] = ((x@emb_w+emb_b)+pos[t]) @ agg_w + agg_b
__global__ void k_embed(const float* __restrict__ x, const float* __restrict__ emb_w,
                        const float* __restrict__ emb_b, const float* __restrict__ pos_emb,
                        const float* __restrict__ agg_w, const float* __restrict__ agg_b,
                        float* __restrict__ X, int n0, int nc)
{
    __shared__ float s_emb[3*DD], s_agg[DD*DD], s_eb[DD], s_ab[DD];
    for (int i = threadIdx.x; i < 3*DD; i += 256) s_emb[i] = emb_w[i];
    for (int i = threadIdx.x; i < DD*DD; i += 256) s_agg[i] = agg_w[i];
    if (threadIdx.x < DD) { s_eb[threadIdx.x]=emb_b[threadIdx.x]; s_ab[threadIdx.x]=agg_b[threadIdx.x]; }
    __syncthreads();
    int idx = blockIdx.x*256 + threadIdx.x;           // nl*TT + t
    if (idx >= nc*TT) return;
    int nl = idx / TT, t = idx % TT;
    int n = n0 + nl;
    int b = n / LL, l = n % LL;
    const float* xp = x + (((size_t)(b*TT + t))*LL + l)*3;
    float x0=xp[0], x1=xp[1], x2=xp[2];
    const float* pe = pos_emb + (size_t)t*DD;
    float tmp[DD];
    #pragma unroll
    for (int d=0; d<DD; ++d)
        tmp[d] = x0*s_emb[0*DD+d] + x1*s_emb[1*DD+d] + x2*s_emb[2*DD+d] + s_eb[d] + pe[d];
    float* Xr = X + ((size_t)nl*TT + t)*DD;
    #pragma unroll
    for (int dd=0; dd<DD; ++dd) {
        float acc = s_ab[dd];
        #pragma unroll
        for (int d=0; d<DD; ++d) acc += tmp[d]*s_agg[d*DD+dd];
        Xr[dd] = acc;
    }
}

// ---------------- rms_norm + in_proj; stores raw xin (cols 0..63) and silu(z) (cols 64..127)
__global__ void k_rmsproj(const float* __restrict__ X, const float* __restrict__ norm_w,
                          const float* __restrict__ in_w,  // (DD, 2*EDm)
                          float* __restrict__ xin_raw, float* __restrict__ zs, int nrows)
{
    __shared__ float s_w[DD*2*EDm];       // 16 KB
    __shared__ float s_xr[2][DD], s_xn[2][DD];
    __shared__ float s_nw[DD];
    for (int i=threadIdx.x; i<DD*2*EDm; i+=256) s_w[i]=in_w[i];
    if (threadIdx.x < DD) s_nw[threadIdx.x] = norm_w[threadIdx.x];
    __syncthreads();
    int r = threadIdx.x>>7, c = threadIdx.x&127;
    int npairs = (nrows+1)>>1;
    for (int pair = blockIdx.x; pair < npairs; pair += gridDim.x){
        int row = pair*2 + r;
        bool valid = row < nrows;
        if (valid && c<DD){ float v = X[(size_t)row*DD+c]; s_xr[r][c]=v; s_xn[r][c]=v*s_nw[c]; }
        __syncthreads();
        if (valid){
            float ss=0.f;
            #pragma unroll
            for (int d2=0;d2<DD;++d2) ss += s_xr[r][d2]*s_xr[r][d2];
            float sc = rsqrtf(ss*(1.0f/DD)+1e-5f);
            float acc=0.f;
            #pragma unroll
            for (int d2=0;d2<DD;++d2) acc += s_xn[r][d2]*s_w[d2*(2*EDm)+c];
            acc *= sc;
            if (c<EDm) xin_raw[(size_t)row*EDm+c]=acc;
            else       zs[(size_t)row*EDm+(c-EDm)]=silu_(acc);
        }
        __syncthreads();
    }
}

// ---------------- causal conv(4) + silu + x_proj -> xin_c, dbc
__global__ void k_convxproj(const float* __restrict__ xin_raw, const float* __restrict__ conv_w, // (EDm,DCm)
                            const float* __restrict__ conv_b, const float* __restrict__ x_w,     // (EDm,XJ)
                            float* __restrict__ xin_c, float* __restrict__ dbc, int nrows)
{
    __shared__ float s_xw[EDm*XJ];      // 8.7 KB
    __shared__ float s_xc[4][EDm];
    for (int i=threadIdx.x;i<EDm*XJ;i+=256) s_xw[i]=x_w[i];
    __syncthreads();
    int r = threadIdx.x>>6, e = threadIdx.x&63;
    int nquads = (nrows+3)>>2;
    for (int q = blockIdx.x; q < nquads; q += gridDim.x){
        int row = q*4 + r;
        bool valid = row < nrows;
        float xc = 0.f;
        if (valid){
            int t = row % TT;
            float acc = conv_b[e];
            #pragma unroll
            for (int k=0;k<DCm;k++){
                int tt = t - (DCm-1) + k;
                if (tt >= 0) acc += xin_raw[((size_t)row - (DCm-1) + k)*EDm + e]*conv_w[e*DCm+k];
            }
            xc = silu_(acc);
            xin_c[(size_t)row*EDm + e] = xc;
        }
        s_xc[r][e] = xc;
        __syncthreads();
        if (valid && e < XJ){
            float acc=0.f;
            #pragma unroll
            for (int d=0; d<EDm; ++d) acc += s_xc[r][d]*s_xw[d*XJ + e];
            dbc[(size_t)row*XST + e] = acc;
        }
        __syncthreads();
    }
}

// ---------------- selective scan; block=256 = one n; lane (e, sq): 4 states each.
// overwrites xin_c with yact = (y + D*xin)*silu(z)
__global__ void k_scan(const float* __restrict__ dbc, float* __restrict__ xin_c,
                       const float* __restrict__ zs, const float* __restrict__ dt_w, // (2,EDm)
                       const float* __restrict__ dt_b, const float* __restrict__ A_log, // (EDm,DSm)
                       const float* __restrict__ Dp, int nc)
{
    int n = blockIdx.x;
    if (n >= nc) return;
    int e = threadIdx.x >> 2;
    int sq = threadIdx.x & 3;
    float A0 = -__expf(A_log[e*DSm + sq*4 + 0]);
    float A1 = -__expf(A_log[e*DSm + sq*4 + 1]);
    float A2 = -__expf(A_log[e*DSm + sq*4 + 2]);
    float A3 = -__expf(A_log[e*DSm + sq*4 + 3]);
    float w0 = dt_w[e], w1 = dt_w[EDm + e], bb = dt_b[e];
    float dpe = Dp[e];
    float h0=0.f,h1=0.f,h2=0.f,h3=0.f;
    const float* dr = dbc + (size_t)n*TT*XST;
    float* xr = xin_c + (size_t)n*TT*EDm;
    const float* zr = zs + (size_t)n*TT*EDm;
    for (int t=0;t<TT;++t){
        const float* d = dr + t*XST;
        float d0 = d[0], d1 = d[1];
        float delta = softpl_(d0*w0 + d1*w1 + bb);
        float u = xr[t*EDm + e];
        float du = delta*u;
        const float* Bp = d + 2 + sq*4;
        const float* Cp = d + 2 + DSm + sq*4;
        float yp;
        h0 = __expf(delta*A0)*h0 + du*Bp[0]; yp  = h0*Cp[0];
        h1 = __expf(delta*A1)*h1 + du*Bp[1]; yp += h1*Cp[1];
        h2 = __expf(delta*A2)*h2 + du*Bp[2]; yp += h2*Cp[2];
        h3 = __expf(delta*A3)*h3 + du*Bp[3]; yp += h3*Cp[3];
        yp += __shfl_xor(yp,1);
        yp += __shfl_xor(yp,2);
        if (sq==0){
            float y = yp + dpe*u;
            xr[t*EDm + e] = y * zr[t*EDm + e];
        }
    }
}

// ---------------- out_proj + residual into X
__global__ void k_outproj(const float* __restrict__ yact, const float* __restrict__ out_w, // (EDm,DD)
                          float* __restrict__ X, int nrows)
{
    __shared__ float s_w[EDm*DD];   // 8 KB
    __shared__ float s_y[8*EDm];
    for (int i=threadIdx.x;i<EDm*DD;i+=256) s_w[i]=out_w[i];
    __syncthreads();
    int r = threadIdx.x>>5, dcol = threadIdx.x&31;
    int ngroups = (nrows+7)>>3;
    for (int g = blockIdx.x; g < ngroups; g += gridDim.x){
        for (int i=threadIdx.x; i<8*EDm; i+=256){
            int rr = i>>6;
            size_t rw = (size_t)g*8 + rr;
            s_y[i] = (rw < (size_t)nrows) ? yact[rw*EDm + (i&63)] : 0.f;
        }
        __syncthreads();
        size_t row = (size_t)g*8 + r;
        if (row < (size_t)nrows){
            float acc=0.f;
            #pragma unroll
            for (int e2=0;e2<EDm;++e2) acc += s_y[r*EDm+e2]*s_w[e2*DD+dcol];
            X[row*DD + dcol] += acc;
        }
        __syncthreads();
    }
}

// ---------------- final: FFN + LN2 + gate-fuse + fc, only at t = TT-1
__global__ void k_final(const float* __restrict__ X, const float* __restrict__ w1, const float* __restrict__ b1,
                        const float* __restrict__ w2, const float* __restrict__ b2,
                        const float* __restrict__ g2, const float* __restrict__ bt2,
                        const float* __restrict__ ln1_b, const float* __restrict__ fgate,
                        const float* __restrict__ fcw, const float* __restrict__ fcb,
                        float* __restrict__ out, int n0, int nc)
{
    int nl = blockIdx.x*256 + threadIdx.x;
    if (nl >= nc) return;
    int n = n0 + nl;
    int b = n / LL, l = n % LL;
    const float* rowp = X + ((size_t)nl*TT + (TT-1))*DD;
    float row[DD];
    #pragma unroll
    for (int d=0; d<DD; ++d) row[d] = rowp[d];
    float ff = b2[0];
    #pragma unroll
    for (int j=0;j<DD;++j){
        float hj = b1[j];
        #pragma unroll
        for (int d=0;d<DD;++d) hj += row[d]*w1[d*DD+j];
        ff += fmaxf(hj,0.f)*w2[j];
    }
    float mu=0.f;
    float r2[DD];
    #pragma unroll
    for (int d=0;d<DD;++d){ r2[d]=row[d]+ff; mu += r2[d]; }
    mu *= (1.0f/DD);
    float var=0.f;
    #pragma unroll
    for (int d=0;d<DD;++d){ float dv=r2[d]-mu; var += dv*dv; }
    var *= (1.0f/DD);
    float sc = rsqrtf(var+1e-5f);
    float gate = sigm_(fgate[l]);
    float acc=0.f;
    #pragma unroll
    for (int d=0;d<DD;++d){
        float xl = (r2[d]-mu)*sc*g2[d] + bt2[d];
        float fused = gate*ln1_b[d] + (1.0f-gate)*xl;
        acc += fused*fcw[d];
    }
    out[b*LL + l] = acc + fcb[0];
}

extern "C" void kernel_launch(void* const* d_in, const int* in_sizes, int n_in,
                              void* d_out, int out_size, void* d_ws, size_t ws_size,
                              hipStream_t stream)
{
    const float* x      = (const float*)d_in[0];
    const float* emb_w  = (const float*)d_in[1];
    const float* emb_b  = (const float*)d_in[2];
    const float* pos    = (const float*)d_in[3];
    const float* agg_w  = (const float*)d_in[4];
    const float* agg_b  = (const float*)d_in[5];
    // d_in[6] sim_w  — unused (attention branch is identically zero at t=T-1)
    // d_in[7] ln1_g  — unused (multiplies zero-variance input; LN(0) = ln1_b)
    const float* ln1_b  = (const float*)d_in[8];
    const float* mnw    = (const float*)d_in[9];   // (2,32)
    const float* minw   = (const float*)d_in[10];  // (2,32,128)
    const float* mcw    = (const float*)d_in[11];  // (2,64,4)
    const float* mcb    = (const float*)d_in[12];  // (2,64)
    const float* mxw    = (const float*)d_in[13];  // (2,64,34)
    const float* mdtw   = (const float*)d_in[14];  // (2,2,64)
    const float* mdtb   = (const float*)d_in[15];  // (2,64)
    const float* mAlog  = (const float*)d_in[16];  // (2,64,16)
    const float* mD     = (const float*)d_in[17];  // (2,64)
    const float* mow    = (const float*)d_in[18];  // (2,64,32)
    const float* fw1    = (const float*)d_in[19];
    const float* fb1    = (const float*)d_in[20];
    const float* fw2    = (const float*)d_in[21];
    const float* fb2    = (const float*)d_in[22];
    const float* g2     = (const float*)d_in[23];
    const float* bt2    = (const float*)d_in[24];
    const float* fgate  = (const float*)d_in[25];  // (366,1)
    const float* fcw    = (const float*)d_in[26];
    const float* fcb    = (const float*)d_in[27];
    float* out = (float*)d_out;
    (void)in_sizes; (void)n_in; (void)out_size;

    // per-sequence scratch: X(T*D) + xin_raw(T*ED) + xin_c(T*ED) + zs(T*ED) + dbc(T*36)
    const size_t perN = (size_t)TT*(DD + 3*EDm + XST)*sizeof(float); // 299,520 B
    int Nc = (int)(ws_size / perN);
    if (Nc > NN) Nc = NN;
    if (Nc < 1)  Nc = 1;

    float* Xb   = (float*)d_ws;
    float* xraw = Xb   + (size_t)Nc*TT*DD;
    float* xc   = xraw + (size_t)Nc*TT*EDm;
    float* zsb  = xc   + (size_t)Nc*TT*EDm;
    float* dbcb = zsb  + (size_t)Nc*TT*EDm;

    for (int n0 = 0; n0 < NN; n0 += Nc) {
        int nc = NN - n0 < Nc ? NN - n0 : Nc;
        int rows = nc*TT;
        int gA = (rows+255)/256;
        k_embed<<<gA, 256, 0, stream>>>(x, emb_w, emb_b, pos, agg_w, agg_b, Xb, n0, nc);
        for (int layer=0; layer<2; ++layer){
            int gP = (rows+1)/2;   if (gP > 4096) gP = 4096;
            int gC = (rows+3)/4;   if (gC > 4096) gC = 4096;
            int gO = (rows+7)/8;   if (gO > 4096) gO = 4096;
            k_rmsproj  <<<gP, 256, 0, stream>>>(Xb, mnw + layer*DD, minw + (size_t)layer*DD*2*EDm,
                                                xraw, zsb, rows);
            k_convxproj<<<gC, 256, 0, stream>>>(xraw, mcw + layer*EDm*DCm, mcb + layer*EDm,
                                                mxw + (size_t)layer*EDm*XJ, xc, dbcb, rows);
            k_scan     <<<nc, 256, 0, stream>>>(dbcb, xc, zsb, mdtw + layer*2*EDm, mdtb + layer*EDm,
                                                mAlog + layer*EDm*DSm, mD + layer*EDm, nc);
            k_outproj  <<<gO, 256, 0, stream>>>(xc, mow + (size_t)layer*EDm*DD, Xb, rows);
        }
        k_final<<<(nc+255)/256, 256, 0, stream>>>(Xb, fw1, fb1, fw2, fb2, g2, bt2,
                                                  ln1_b, fgate, fcw, fcb, out, n0, nc);
    }
}

// Round 2
// 686.882 us; speedup vs baseline: 1.3862x; 1.3862x over previous
//
#include <hip/hip_runtime.h>
#include <math.h>

#define TT 288
#define LL 366
#define BBn 2
#define NN (BBn*LL)   // 732
#define DD 32
#define EDm 64
#define DSm 16
#define DCm 4
#define XJ 34         // dt_rank + 2*DS
#define XST 36        // padded dbc row stride
#define CH 16
#define NCH (TT/CH)   // 18

__device__ __forceinline__ float sigm_(float x){ return 1.0f/(1.0f+__expf(-x)); }
__device__ __forceinline__ float silu_(float x){ return x*sigm_(x); }
__device__ __forceinline__ float softpl_(float x){ return fmaxf(x,0.0f) + __logf(1.0f + __expf(-fabsf(x))); }

// ---------------- embed: X[nl,t,d] = ((x@emb_w+emb_b)+pos[t]) @ agg_w + agg_b
__global__ void k_embed(const float* __restrict__ x, const float* __restrict__ emb_w,
                        const float* __restrict__ emb_b, const float* __restrict__ pos_emb,
                        const float* __restrict__ agg_w, const float* __restrict__ agg_b,
                        float* __restrict__ X)
{
    __shared__ float s_emb[3*DD], s_agg[DD*DD], s_eb[DD], s_ab[DD];
    for (int i = threadIdx.x; i < 3*DD; i += 256) s_emb[i] = emb_w[i];
    for (int i = threadIdx.x; i < DD*DD; i += 256) s_agg[i] = agg_w[i];
    if (threadIdx.x < DD) { s_eb[threadIdx.x]=emb_b[threadIdx.x]; s_ab[threadIdx.x]=agg_b[threadIdx.x]; }
    __syncthreads();
    int idx = blockIdx.x*256 + threadIdx.x;           // n*TT + t
    if (idx >= NN*TT) return;
    int n = idx / TT, t = idx % TT;
    int b = n / LL, l = n % LL;
    const float* xp = x + (((size_t)(b*TT + t))*LL + l)*3;
    float x0=xp[0], x1=xp[1], x2=xp[2];
    const float* pe = pos_emb + (size_t)t*DD;
    float tmp[DD];
    #pragma unroll
    for (int d=0; d<DD; ++d)
        tmp[d] = x0*s_emb[0*DD+d] + x1*s_emb[1*DD+d] + x2*s_emb[2*DD+d] + s_eb[d] + pe[d];
    float* Xr = X + ((size_t)n*TT + t)*DD;
    #pragma unroll
    for (int dd=0; dd<DD; ++dd) {
        float acc = s_ab[dd];
        #pragma unroll
        for (int d=0; d<DD; ++d) acc += tmp[d]*s_agg[d*DD+dd];
        Xr[dd] = acc;
    }
}

// ---------------- fully-fused mamba layer: block = one sequence n
// X <- X + out_proj( scan( conv/silu/xproj( in_proj( rmsnorm(X) ) ) ) * silu(z) )
__global__ __launch_bounds__(256,3) void k_layer(
    float* __restrict__ X,
    const float* __restrict__ norm_w, const float* __restrict__ in_w,   // (DD,128)
    const float* __restrict__ conv_w, const float* __restrict__ conv_b, // (EDm,DCm),(EDm)
    const float* __restrict__ x_w,                                      // (EDm,XJ)
    const float* __restrict__ dt_w, const float* __restrict__ dt_b,     // (2,EDm),(EDm)
    const float* __restrict__ A_log, const float* __restrict__ Dp,      // (EDm,DSm),(EDm)
    const float* __restrict__ out_w)                                    // (EDm,DD)
{
    __shared__ __attribute__((aligned(16))) float s_inw[DD*2*EDm]; // [d][j] 16KB
    __shared__ float s_xw[EDm*XJ];        // [e][j] 8.5KB
    __shared__ float s_ow[EDm*DD];        // [e][d] 8KB
    __shared__ float s_nw[DD];
    __shared__ float s_cwt[DCm*EDm];      // [k][e] transposed conv weights
    __shared__ float s_cb[EDm];
    __shared__ float s_dtw[2*EDm];
    __shared__ float s_dtb[EDm];
    __shared__ float s_dp[EDm];
    __shared__ __attribute__((aligned(16))) float s_xn[CH][DD];    // 2KB
    __shared__ __attribute__((aligned(16))) float s_xin[CH][EDm];  // 4KB
    __shared__ __attribute__((aligned(16))) float s_xc[CH][EDm];   // 4KB (u, then gated y)
    __shared__ __attribute__((aligned(16))) float s_z[CH][EDm];    // 4KB
    __shared__ float s_dbc[CH][XST];      // 2.25KB
    __shared__ float s_hist[DCm-1][EDm];  // conv history

    const int tid = threadIdx.x;
    const int n = blockIdx.x;

    for (int i=tid;i<DD*2*EDm;i+=256) s_inw[i]=in_w[i];
    for (int i=tid;i<EDm*XJ;i+=256)   s_xw[i]=x_w[i];
    for (int i=tid;i<EDm*DD;i+=256)   s_ow[i]=out_w[i];
    for (int i=tid;i<DCm*EDm;i+=256){ int k=i>>6, e=i&63; s_cwt[i]=conv_w[e*DCm+k]; }
    if (tid<DD) s_nw[tid]=norm_w[tid];
    if (tid<EDm){ s_cb[tid]=conv_b[tid]; s_dtb[tid]=dt_b[tid]; s_dp[tid]=Dp[tid]; }
    if (tid<2*EDm) s_dtw[tid]=dt_w[tid];
    for (int i=tid;i<(DCm-1)*EDm;i+=256) ((float*)s_hist)[i]=0.f;

    const int e_s = tid>>2, sq = tid&3;   // scan lane layout
    const float A0 = -__expf(A_log[e_s*DSm+sq*4+0]);
    const float A1 = -__expf(A_log[e_s*DSm+sq*4+1]);
    const float A2 = -__expf(A_log[e_s*DSm+sq*4+2]);
    const float A3 = -__expf(A_log[e_s*DSm+sq*4+3]);
    float h0=0.f,h1=0.f,h2=0.f,h3=0.f;
    __syncthreads();

    float* Xn = X + (size_t)n*TT*DD;

    for (int ch=0; ch<NCH; ++ch){
        const int t0 = ch*CH;
        // ---- A: load X chunk + rmsnorm (row = 32 consecutive lanes)
        #pragma unroll
        for (int i=0;i<2;++i){
            int idx = tid + i*256;
            int r = idx>>5, c = idx&31;
            float v = Xn[(t0+r)*DD + c];
            float ss = v*v;
            ss += __shfl_xor(ss,1);  ss += __shfl_xor(ss,2);
            ss += __shfl_xor(ss,4);  ss += __shfl_xor(ss,8);
            ss += __shfl_xor(ss,16);
            float sc = rsqrtf(ss*(1.0f/DD)+1e-5f);
            s_xn[r][c] = v*sc*s_nw[c];
        }
        __syncthreads();
        // ---- B: in_proj (16 rows x 128 cols; thread = 1 row x 8 cols)
        {
            int r  = tid>>4;
            int c8 = (tid&15)*8;
            float acc[8] = {0,0,0,0,0,0,0,0};
            #pragma unroll
            for (int d=0; d<DD; ++d){
                float xv = s_xn[r][d];
                const float4* wq = (const float4*)&s_inw[d*(2*EDm)+c8];
                float4 wa = wq[0], wb = wq[1];
                acc[0]+=xv*wa.x; acc[1]+=xv*wa.y; acc[2]+=xv*wa.z; acc[3]+=xv*wa.w;
                acc[4]+=xv*wb.x; acc[5]+=xv*wb.y; acc[6]+=xv*wb.z; acc[7]+=xv*wb.w;
            }
            if (c8 < EDm){
                #pragma unroll
                for (int k=0;k<8;++k) s_xin[r][c8+k]=acc[k];
            } else {
                #pragma unroll
                for (int k=0;k<8;++k) s_z[r][c8-EDm+k]=silu_(acc[k]);
            }
        }
        __syncthreads();
        // ---- C: causal conv(4) + silu
        {
            int e = tid&63, r4 = tid>>6;
            #pragma unroll
            for (int k=0;k<4;++k){
                int r = r4*4+k;
                float acc = s_cb[e];
                #pragma unroll
                for (int kk=0;kk<DCm;++kk){
                    int rr = r - (DCm-1) + kk;
                    float xv = (rr>=0) ? s_xin[rr][e] : s_hist[3+rr][e];
                    acc += xv*s_cwt[kk*EDm+e];
                }
                s_xc[r][e] = silu_(acc);
            }
        }
        __syncthreads();
        // ---- D: conv-history update + x_proj (16 rows x 34 cols)
        if (tid < (DCm-1)*EDm){
            int k = tid>>6, e = tid&63;
            s_hist[k][e] = s_xin[CH-(DCm-1)+k][e];
        }
        for (int idx=tid; idx<CH*XJ; idx+=256){
            int r = idx/XJ, j = idx - r*XJ;
            const float4* xcp = (const float4*)&s_xc[r][0];
            float acc=0.f;
            #pragma unroll
            for (int q=0;q<16;++q){
                float4 a = xcp[q];
                acc += a.x*s_xw[(4*q+0)*XJ+j];
                acc += a.y*s_xw[(4*q+1)*XJ+j];
                acc += a.z*s_xw[(4*q+2)*XJ+j];
                acc += a.w*s_xw[(4*q+3)*XJ+j];
            }
            s_dbc[r][j]=acc;
        }
        __syncthreads();
        // ---- E: selective scan over CH steps (thread = (e, 4-state quarter))
        {
            float w0 = s_dtw[e_s], w1 = s_dtw[EDm+e_s], bb = s_dtb[e_s];
            float dpe = s_dp[e_s];
            #pragma unroll
            for (int t=0;t<CH;++t){
                float d0 = s_dbc[t][0], d1 = s_dbc[t][1];
                float delta = softpl_(d0*w0 + d1*w1 + bb);
                float u = s_xc[t][e_s];
                float du = delta*u;
                const float* Bp = &s_dbc[t][2+sq*4];
                const float* Cp = &s_dbc[t][2+DSm+sq*4];
                float yp;
                h0 = __expf(delta*A0)*h0 + du*Bp[0]; yp  = h0*Cp[0];
                h1 = __expf(delta*A1)*h1 + du*Bp[1]; yp += h1*Cp[1];
                h2 = __expf(delta*A2)*h2 + du*Bp[2]; yp += h2*Cp[2];
                h3 = __expf(delta*A3)*h3 + du*Bp[3]; yp += h3*Cp[3];
                yp += __shfl_xor(yp,1);
                yp += __shfl_xor(yp,2);
                if (sq==0){
                    float y = yp + dpe*u;
                    s_xc[t][e_s] = y * s_z[t][e_s];   // same-wave readers already consumed u
                }
            }
        }
        __syncthreads();
        // ---- F: out_proj + residual (16 rows x 32 cols; thread = 2 outputs)
        #pragma unroll
        for (int i=0;i<2;++i){
            int idx = tid + i*256;
            int r = idx>>5, c = idx&31;
            const float4* yp4 = (const float4*)&s_xc[r][0];
            float acc=0.f;
            #pragma unroll
            for (int q=0;q<16;++q){
                float4 a = yp4[q];
                acc += a.x*s_ow[(4*q+0)*DD+c];
                acc += a.y*s_ow[(4*q+1)*DD+c];
                acc += a.z*s_ow[(4*q+2)*DD+c];
                acc += a.w*s_ow[(4*q+3)*DD+c];
            }
            Xn[(t0+r)*DD+c] += acc;
        }
        __syncthreads();
    }
}

// ---------------- final: FFN + LN2 + gate-fuse + fc, only at t = TT-1
__global__ void k_final(const float* __restrict__ X, const float* __restrict__ w1, const float* __restrict__ b1,
                        const float* __restrict__ w2, const float* __restrict__ b2,
                        const float* __restrict__ g2, const float* __restrict__ bt2,
                        const float* __restrict__ ln1_b, const float* __restrict__ fgate,
                        const float* __restrict__ fcw, const float* __restrict__ fcb,
                        float* __restrict__ out)
{
    int n = blockIdx.x*256 + threadIdx.x;
    if (n >= NN) return;
    int b = n / LL, l = n % LL;
    const float* rowp = X + ((size_t)n*TT + (TT-1))*DD;
    float row[DD];
    #pragma unroll
    for (int d=0; d<DD; ++d) row[d] = rowp[d];
    float ff = b2[0];
    #pragma unroll
    for (int j=0;j<DD;++j){
        float hj = b1[j];
        #pragma unroll
        for (int d=0;d<DD;++d) hj += row[d]*w1[d*DD+j];
        ff += fmaxf(hj,0.f)*w2[j];
    }
    float mu=0.f;
    float r2[DD];
    #pragma unroll
    for (int d=0;d<DD;++d){ r2[d]=row[d]+ff; mu += r2[d]; }
    mu *= (1.0f/DD);
    float var=0.f;
    #pragma unroll
    for (int d=0;d<DD;++d){ float dv=r2[d]-mu; var += dv*dv; }
    var *= (1.0f/DD);
    float sc = rsqrtf(var+1e-5f);
    float gate = sigm_(fgate[l]);
    float acc=0.f;
    #pragma unroll
    for (int d=0;d<DD;++d){
        float xl = (r2[d]-mu)*sc*g2[d] + bt2[d];
        float fused = gate*ln1_b[d] + (1.0f-gate)*xl;
        acc += fused*fcw[d];
    }
    out[b*LL + l] = acc + fcb[0];
}

extern "C" void kernel_launch(void* const* d_in, const int* in_sizes, int n_in,
                              void* d_out, int out_size, void* d_ws, size_t ws_size,
                              hipStream_t stream)
{
    const float* x      = (const float*)d_in[0];
    const float* emb_w  = (const float*)d_in[1];
    const float* emb_b  = (const float*)d_in[2];
    const float* pos    = (const float*)d_in[3];
    const float* agg_w  = (const float*)d_in[4];
    const float* agg_b  = (const float*)d_in[5];
    // d_in[6] sim_w  — unused (attention branch is identically zero at t=T-1)
    // d_in[7] ln1_g  — unused (LN of all-zero input = ln1_b)
    const float* ln1_b  = (const float*)d_in[8];
    const float* mnw    = (const float*)d_in[9];   // (2,32)
    const float* minw   = (const float*)d_in[10];  // (2,32,128)
    const float* mcw    = (const float*)d_in[11];  // (2,64,4)
    const float* mcb    = (const float*)d_in[12];  // (2,64)
    const float* mxw    = (const float*)d_in[13];  // (2,64,34)
    const float* mdtw   = (const float*)d_in[14];  // (2,2,64)
    const float* mdtb   = (const float*)d_in[15];  // (2,64)
    const float* mAlog  = (const float*)d_in[16];  // (2,64,16)
    const float* mD     = (const float*)d_in[17];  // (2,64)
    const float* mow    = (const float*)d_in[18];  // (2,64,32)
    const float* fw1    = (const float*)d_in[19];
    const float* fb1    = (const float*)d_in[20];
    const float* fw2    = (const float*)d_in[21];
    const float* fb2    = (const float*)d_in[22];
    const float* g2     = (const float*)d_in[23];
    const float* bt2    = (const float*)d_in[24];
    const float* fgate  = (const float*)d_in[25];  // (366,1)
    const float* fcw    = (const float*)d_in[26];
    const float* fcb    = (const float*)d_in[27];
    float* out = (float*)d_out;
    (void)in_sizes; (void)n_in; (void)out_size; (void)ws_size;

    float* Xb = (float*)d_ws;   // NN*TT*DD floats = 27 MB (ws >= 110MB per round-1 behavior)

    k_embed<<<(NN*TT+255)/256, 256, 0, stream>>>(x, emb_w, emb_b, pos, agg_w, agg_b, Xb);
    for (int layer=0; layer<2; ++layer){
        k_layer<<<NN, 256, 0, stream>>>(Xb,
            mnw  + layer*DD,
            minw + (size_t)layer*DD*2*EDm,
            mcw  + layer*EDm*DCm,
            mcb  + layer*EDm,
            mxw  + (size_t)layer*EDm*XJ,
            mdtw + layer*2*EDm,
            mdtb + layer*EDm,
            mAlog+ layer*EDm*DSm,
            mD   + layer*EDm,
            mow  + (size_t)layer*EDm*DD);
    }
    k_final<<<(NN+255)/256, 256, 0, stream>>>(Xb, fw1, fb1, fw2, fb2, g2, bt2,
                                              ln1_b, fgate, fcw, fcb, out);
}